// Round 19
// baseline (364.063 us; speedup 1.0000x reference)
//
#include <hip/hip_runtime.h>
#include <cmath>

// N=50000, E=800000, B=1, F=D=64, H=4, d=16, M=8.
// Edge kernels: lane = (head h=l>>4, edge-slot e=l&15). 16 edges/step/wave.
// MLP EXPERIMENT: each wave processes TWO nodes, edge-gather loops interleaved
// so 8 scattered uint4 loads are in flight per wave (was 4). Post-phases
// (softmax reduce / wave-private LDS transpose / MLP) sequential per node.

__device__ __forceinline__ float softplus_f(float z){
  return fmaxf(z, 0.f) + log1pf(__expf(-fabsf(z)));
}
__device__ __forceinline__ unsigned short f2bf(float x){   // RNE bf16
  unsigned int u = __float_as_uint(x);
  unsigned int r = (u + 0x7fffu + ((u>>16)&1u)) >> 16;
  return (unsigned short)r;
}
__device__ __forceinline__ unsigned int pack2bf(float a, float b){
  return (unsigned int)f2bf(a) | ((unsigned int)f2bf(b) << 16);
}
__device__ __forceinline__ float bflo(unsigned int u){ return __uint_as_float(u << 16); }
__device__ __forceinline__ float bfhi(unsigned int u){ return __uint_as_float(u & 0xffff0000u); }

// ---------------- K1: projections, W staged in LDS. Q f32; K,T -> KT16; V -> Vfi16
__global__ __launch_bounds__(256) void k_proj(
    const float* __restrict__ x_src, const float* __restrict__ x_dst,
    const float* __restrict__ Wq, const float* __restrict__ Wk,
    const float* __restrict__ Wt, const float* __restrict__ Wv,
    const float* __restrict__ We,
    float* __restrict__ Qo, unsigned short* __restrict__ KT16,
    unsigned short* __restrict__ Vfi16, float* __restrict__ WeQ, int N)
{
  __shared__ float sW[4*4096];
  int tid = threadIdx.x;
  {
    float4* dW = (float4*)sW;
    const float4* s0 = (const float4*)Wq;
    const float4* s1 = (const float4*)Wk;
    const float4* s2 = (const float4*)Wt;
    const float4* s3 = (const float4*)Wv;
    #pragma unroll
    for (int i=tid; i<1024; i+=256) dW[i]      = s0[i];
    #pragma unroll
    for (int i=tid; i<1024; i+=256) dW[1024+i] = s1[i];
    #pragma unroll
    for (int i=tid; i<1024; i+=256) dW[2048+i] = s2[i];
    #pragma unroll
    for (int i=tid; i<1024; i+=256) dW[3072+i] = s3[i];
  }
  __syncthreads();

  int l   = tid & 63;
  int mat = __builtin_amdgcn_readfirstlane(tid >> 6);
  int n   = blockIdx.x * 64 + l;
  if (n < N){
    const float* x = ((mat==0) ? x_dst : x_src) + (size_t)n*64;
    const float4* Wm4 = (const float4*)(sW + (mat<<12));
    const float4* We4 = (const float4*)We;

    float xr[64];
    const float4* x4 = (const float4*)x;
    #pragma unroll
    for (int i=0;i<16;i++){ float4 v=x4[i]; xr[4*i]=v.x; xr[4*i+1]=v.y; xr[4*i+2]=v.z; xr[4*i+3]=v.w; }

    float4* Q4 = (float4*)(Qo + (size_t)n*64);
    float weq0=0.f, weq1=0.f, weq2=0.f, weq3=0.f;
    #pragma unroll
    for (int jq=0;jq<16;jq++){
      float a0=0.f,a1=0.f,a2=0.f,a3=0.f;
      const float4* Wr4 = Wm4 + jq*64;
      #pragma unroll
      for (int f4=0;f4<16;f4++){
        float4 w0 = Wr4[f4], w1 = Wr4[16+f4], w2 = Wr4[32+f4], w3 = Wr4[48+f4];
        float x0=xr[4*f4], x1=xr[4*f4+1], x2=xr[4*f4+2], x3=xr[4*f4+3];
        a0=fmaf(w0.x,x0,a0); a0=fmaf(w0.y,x1,a0); a0=fmaf(w0.z,x2,a0); a0=fmaf(w0.w,x3,a0);
        a1=fmaf(w1.x,x0,a1); a1=fmaf(w1.y,x1,a1); a1=fmaf(w1.z,x2,a1); a1=fmaf(w1.w,x3,a1);
        a2=fmaf(w2.x,x0,a2); a2=fmaf(w2.y,x1,a2); a2=fmaf(w2.z,x2,a2); a2=fmaf(w2.w,x3,a2);
        a3=fmaf(w3.x,x0,a3); a3=fmaf(w3.y,x1,a3); a3=fmaf(w3.z,x2,a3); a3=fmaf(w3.w,x3,a3);
      }
      int hq = jq>>2, sq = jq&3;
      if (mat==0){
        Q4[jq] = make_float4(a0,a1,a2,a3);
        float4 we = We4[jq];
        float ws = we.x*a0 + we.y*a1 + we.z*a2 + we.w*a3;
        if      (jq <  4) weq0 += ws;
        else if (jq <  8) weq1 += ws;
        else if (jq < 12) weq2 += ws;
        else              weq3 += ws;
      } else if (mat==1){
        *(uint2*)(KT16 + (size_t)n*128 + hq*32 + sq*4) = make_uint2(pack2bf(a0,a1), pack2bf(a2,a3));
      } else if (mat==2){
        *(uint2*)(KT16 + (size_t)n*128 + hq*32 + 16 + sq*4) = make_uint2(pack2bf(a0,a1), pack2bf(a2,a3));
      } else {
        *(uint2*)(Vfi16 + (size_t)n*96 + hq*24 + sq*4) = make_uint2(pack2bf(a0,a1), pack2bf(a2,a3));
      }
    }
    if (mat==0) *(float4*)(WeQ + (size_t)n*4) = make_float4(weq0,weq1,weq2,weq3);
  }
}

// ---------------- CSR build
__global__ __launch_bounds__(256) void k_hist(const int* __restrict__ dst, int* __restrict__ deg, int E){
  int i = blockIdx.x*256 + threadIdx.x;
  if (i < E) atomicAdd(&deg[dst[i]], 1);
}

__global__ __launch_bounds__(1024) void k_scan1(const int* __restrict__ deg, int* __restrict__ rowptr,
                                                int* __restrict__ bsum, int N){
  __shared__ int sh[1024];
  int t = threadIdx.x;
  int i = blockIdx.x*1024 + t;
  int v = (i < N) ? deg[i] : 0;
  sh[t] = v; __syncthreads();
  int x = v;
  for (int off=1; off<1024; off<<=1){
    int y = (t >= off) ? sh[t-off] : 0;
    __syncthreads();
    x += y; sh[t] = x;
    __syncthreads();
  }
  if (i < N) rowptr[i] = x - v;
  if (t == 1023) bsum[blockIdx.x] = x;
}

__global__ __launch_bounds__(64) void k_scan2(int* __restrict__ bsum, int nb){
  int l = threadIdx.x;
  int v0 = (l < nb) ? bsum[l] : 0;
  int v = v0;
  for (int off=1; off<64; off<<=1){
    int y = __shfl_up(v, off);
    if (l >= off) v += y;
  }
  if (l < nb) bsum[l] = v - v0;
}

__global__ __launch_bounds__(1024) void k_scan3(int* __restrict__ rowptr, const int* __restrict__ bsum,
                                                int N, int E){
  int i = blockIdx.x*1024 + threadIdx.x;
  if (i < N) rowptr[i] += bsum[blockIdx.x];
  if (i == 0) rowptr[N] = E;
}

__global__ __launch_bounds__(256) void k_scatter(const int* __restrict__ dst, const int* __restrict__ src,
                                                 const float* __restrict__ ef,
                                                 const int* __restrict__ rowptr,
                                                 int* __restrict__ fill,
                                                 int2* __restrict__ sedge, int E){
  int i = blockIdx.x*256 + threadIdx.x;
  if (i < E){
    int d_ = dst[i];
    int pos = rowptr[d_] + atomicAdd(&fill[d_], 1);
    sedge[pos] = make_int2(src[i], __float_as_int(ef[i]));
  }
}

// ---------------- K5: TWO nodes per wave, interleaved gathers
__global__ __launch_bounds__(256) void k_node(
    const float* __restrict__ Qb, const unsigned short* __restrict__ KT16,
    const float* __restrict__ WeQ, const float* __restrict__ t_in,
    const int* __restrict__ rowptr, const int2* __restrict__ sedge,
    const float* __restrict__ Wi, const float* __restrict__ bi,
    const float* __restrict__ wiw, const float* __restrict__ scale_i,
    float* __restrict__ es, float* __restrict__ esum,
    unsigned short* __restrict__ Vfi16, int N)
{
  __shared__ float sWi[128*17];
  __shared__ float sbi[128];
  __shared__ float swiw[128];
  __shared__ float sscale[8];
  __shared__ float g_sh[4][4][17];
  __shared__ float tr[4][64][9];
  int tid = threadIdx.x;
  for (int i=tid; i<128*17; i+=256) sWi[i] = Wi[i];
  if (tid < 128){ sbi[tid] = bi[tid]; swiw[tid] = wiw[tid]; }
  if (tid < 8)  sscale[tid] = __expf(scale_i[tid]);
  __syncthreads();                       // the ONLY block barrier

  int w = tid>>6, l = tid&63;
  int h = l>>4, e = l&15;
  int n1 = blockIdx.x*8 + w*2;
  int n2 = n1 + 1;
  bool act1 = (n1 < N), act2 = (n2 < N);

  int row1=0, dg1=0, row2=0, dg2=0;
  float q1[16], q2[16];
  float weq1=0.f, weq2=0.f;
  #pragma unroll
  for (int j=0;j<16;j++){ q1[j]=0.f; q2[j]=0.f; }
  if (act1){
    row1 = rowptr[n1]; dg1 = rowptr[n1+1]-row1;
    const float4* q4 = (const float4*)(Qb + (size_t)n1*64 + (h<<4));
    #pragma unroll
    for (int j=0;j<4;j++){
      float4 v=q4[j];
      q1[4*j]=v.x*0.25f; q1[4*j+1]=v.y*0.25f; q1[4*j+2]=v.z*0.25f; q1[4*j+3]=v.w*0.25f;
    }
    weq1 = WeQ[n1*4+h]*0.25f;
  }
  if (act2){
    row2 = rowptr[n2]; dg2 = rowptr[n2+1]-row2;
    const float4* q4 = (const float4*)(Qb + (size_t)n2*64 + (h<<4));
    #pragma unroll
    for (int j=0;j<4;j++){
      float4 v=q4[j];
      q2[4*j]=v.x*0.25f; q2[4*j+1]=v.y*0.25f; q2[4*j+2]=v.z*0.25f; q2[4*j+3]=v.w*0.25f;
    }
    weq2 = WeQ[n2*4+h]*0.25f;
  }

  float sacc1=0.f, sacc2=0.f;
  float gacc1[16], gacc2[16];
  #pragma unroll
  for (int j=0;j<16;j++){ gacc1[j]=0.f; gacc2[j]=0.f; }

  int mdg = max(dg1, dg2);
  for (int c0=0; c0<mdg; c0+=16){
    int cnt1 = dg1-c0, cnt2 = dg2-c0;
    int2 pva = (e < cnt1) ? sedge[row1+c0+e] : make_int2(0,0);
    int2 pvb = (e < cnt2) ? sedge[row2+c0+e] : make_int2(0,0);
    const uint4* Ga = (const uint4*)(KT16 + ((size_t)pva.x<<7) + (h<<5));
    const uint4* Gb = (const uint4*)(KT16 + ((size_t)pvb.x<<7) + (h<<5));
    uint4 ka0=Ga[0], ka1=Ga[1], ta0=Ga[2], ta1=Ga[3];
    uint4 kb0=Gb[0], kb1=Gb[1], tb0=Gb[2], tb1=Gb[3];

    // node1 compute
    {
      float d = 0.f;
      d=fmaf(bflo(ka0.x),q1[0],d);  d=fmaf(bfhi(ka0.x),q1[1],d);
      d=fmaf(bflo(ka0.y),q1[2],d);  d=fmaf(bfhi(ka0.y),q1[3],d);
      d=fmaf(bflo(ka0.z),q1[4],d);  d=fmaf(bfhi(ka0.z),q1[5],d);
      d=fmaf(bflo(ka0.w),q1[6],d);  d=fmaf(bfhi(ka0.w),q1[7],d);
      d=fmaf(bflo(ka1.x),q1[8],d);  d=fmaf(bfhi(ka1.x),q1[9],d);
      d=fmaf(bflo(ka1.y),q1[10],d); d=fmaf(bfhi(ka1.y),q1[11],d);
      d=fmaf(bflo(ka1.z),q1[12],d); d=fmaf(bfhi(ka1.z),q1[13],d);
      d=fmaf(bflo(ka1.w),q1[14],d); d=fmaf(bfhi(ka1.w),q1[15],d);
      float p = __expf(fmaf(__int_as_float(pva.y), weq1, d));
      if (e >= cnt1) p = 0.f;
      if (e < cnt1)  es[(size_t)(row1+c0+e)*4 + h] = p;
      sacc1 += p;
      gacc1[0] =fmaf(bflo(ta0.x),p,gacc1[0]);  gacc1[1] =fmaf(bfhi(ta0.x),p,gacc1[1]);
      gacc1[2] =fmaf(bflo(ta0.y),p,gacc1[2]);  gacc1[3] =fmaf(bfhi(ta0.y),p,gacc1[3]);
      gacc1[4] =fmaf(bflo(ta0.z),p,gacc1[4]);  gacc1[5] =fmaf(bfhi(ta0.z),p,gacc1[5]);
      gacc1[6] =fmaf(bflo(ta0.w),p,gacc1[6]);  gacc1[7] =fmaf(bfhi(ta0.w),p,gacc1[7]);
      gacc1[8] =fmaf(bflo(ta1.x),p,gacc1[8]);  gacc1[9] =fmaf(bfhi(ta1.x),p,gacc1[9]);
      gacc1[10]=fmaf(bflo(ta1.y),p,gacc1[10]); gacc1[11]=fmaf(bfhi(ta1.y),p,gacc1[11]);
      gacc1[12]=fmaf(bflo(ta1.z),p,gacc1[12]); gacc1[13]=fmaf(bfhi(ta1.z),p,gacc1[13]);
      gacc1[14]=fmaf(bflo(ta1.w),p,gacc1[14]); gacc1[15]=fmaf(bfhi(ta1.w),p,gacc1[15]);
    }
    // node2 compute
    {
      float d = 0.f;
      d=fmaf(bflo(kb0.x),q2[0],d);  d=fmaf(bfhi(kb0.x),q2[1],d);
      d=fmaf(bflo(kb0.y),q2[2],d);  d=fmaf(bfhi(kb0.y),q2[3],d);
      d=fmaf(bflo(kb0.z),q2[4],d);  d=fmaf(bfhi(kb0.z),q2[5],d);
      d=fmaf(bflo(kb0.w),q2[6],d);  d=fmaf(bfhi(kb0.w),q2[7],d);
      d=fmaf(bflo(kb1.x),q2[8],d);  d=fmaf(bfhi(kb1.x),q2[9],d);
      d=fmaf(bflo(kb1.y),q2[10],d); d=fmaf(bfhi(kb1.y),q2[11],d);
      d=fmaf(bflo(kb1.z),q2[12],d); d=fmaf(bfhi(kb1.z),q2[13],d);
      d=fmaf(bflo(kb1.w),q2[14],d); d=fmaf(bfhi(kb1.w),q2[15],d);
      float p = __expf(fmaf(__int_as_float(pvb.y), weq2, d));
      if (e >= cnt2) p = 0.f;
      if (e < cnt2)  es[(size_t)(row2+c0+e)*4 + h] = p;
      sacc2 += p;
      gacc2[0] =fmaf(bflo(tb0.x),p,gacc2[0]);  gacc2[1] =fmaf(bfhi(tb0.x),p,gacc2[1]);
      gacc2[2] =fmaf(bflo(tb0.y),p,gacc2[2]);  gacc2[3] =fmaf(bfhi(tb0.y),p,gacc2[3]);
      gacc2[4] =fmaf(bflo(tb0.z),p,gacc2[4]);  gacc2[5] =fmaf(bfhi(tb0.z),p,gacc2[5]);
      gacc2[6] =fmaf(bflo(tb0.w),p,gacc2[6]);  gacc2[7] =fmaf(bfhi(tb0.w),p,gacc2[7]);
      gacc2[8] =fmaf(bflo(tb1.x),p,gacc2[8]);  gacc2[9] =fmaf(bfhi(tb1.x),p,gacc2[9]);
      gacc2[10]=fmaf(bflo(tb1.y),p,gacc2[10]); gacc2[11]=fmaf(bfhi(tb1.y),p,gacc2[11]);
      gacc2[12]=fmaf(bflo(tb1.z),p,gacc2[12]); gacc2[13]=fmaf(bfhi(tb1.z),p,gacc2[13]);
      gacc2[14]=fmaf(bflo(tb1.w),p,gacc2[14]); gacc2[15]=fmaf(bfhi(tb1.w),p,gacc2[15]);
    }
  }

  // post-phase per node (softmax reduce, wave-private transpose, MLP -> fi)
  auto post = [&](bool act, int n, int dg, float sacc, float (&gacc)[16]){
    sacc += __shfl_xor(sacc,1); sacc += __shfl_xor(sacc,2);
    sacc += __shfl_xor(sacc,4); sacc += __shfl_xor(sacc,8);
    if (act && e == 0) esum[n*4 + h] = sacc;
    float invs = (dg > 0) ? 1.f/sacc : 0.f;

    float gval = 0.f;
    *(float4*)&tr[w][l][0] = make_float4(gacc[0],gacc[1],gacc[2],gacc[3]);
    *(float4*)&tr[w][l][4] = make_float4(gacc[4],gacc[5],gacc[6],gacc[7]);
    if (e < 8){
      float s = 0.f;
      #pragma unroll
      for (int ee=0; ee<16; ee++) s += tr[w][(h<<4)+ee][e];
      gval = s;
    }
    *(float4*)&tr[w][l][0] = make_float4(gacc[8],gacc[9],gacc[10],gacc[11]);
    *(float4*)&tr[w][l][4] = make_float4(gacc[12],gacc[13],gacc[14],gacc[15]);
    if (e >= 8){
      float s = 0.f;
      #pragma unroll
      for (int ee=0; ee<16; ee++) s += tr[w][(h<<4)+ee][e-8];
      gval = s;
    }
    if (act){
      g_sh[w][h][e] = gval * invs;
      if (l < 4) g_sh[w][l][16] = t_in[n];
    }

    if (act){
      float wi1[17], wi2[17];
      #pragma unroll
      for (int j=0;j<17;j++){ wi1[j] = sWi[l*17 + j]; wi2[j] = sWi[(l+64)*17 + j]; }
      float b1 = sbi[l],  b2 = sbi[l+64];
      float wv1 = swiw[l], wv2 = swiw[l+64];
      float z1[4], z2[4];
      #pragma unroll
      for (int h2=0; h2<4; h2++){
        float a1=b1, a2=b2;
        #pragma unroll
        for (int j=0;j<17;j++){
          float inj = g_sh[w][h2][j];
          a1 = fmaf(wi1[j], inj, a1);
          a2 = fmaf(wi2[j], inj, a2);
        }
        float u1 = __fdividef(1.f, 1.f + __expf(-a1));
        float u2 = __fdividef(1.f, 1.f + __expf(-a2));
        float p1 = u1*wv1, p2 = u2*wv2;
        p1 += __shfl_xor(p1,1); p1 += __shfl_xor(p1,2); p1 += __shfl_xor(p1,4); p1 += __shfl_xor(p1,8);
        p2 += __shfl_xor(p2,1); p2 += __shfl_xor(p2,2); p2 += __shfl_xor(p2,4); p2 += __shfl_xor(p2,8);
        z1[h2] = p1; z2[h2] = p2;
      }
      if (e == 0){
        int m1 = h;
        float sc1 = sscale[m1], sc2 = sscale[m1+4];
        #pragma unroll
        for (int h2=0; h2<4; h2++){
          Vfi16[(size_t)n*96 + h2*24 + 16 + m1    ] = f2bf(sc1*softplus_f(z1[h2]/sc1));
          Vfi16[(size_t)n*96 + h2*24 + 16 + m1 + 4] = f2bf(sc2*softplus_f(z2[h2]/sc2));
        }
      }
    }
  };
  post(act1, n1, dg1, sacc1, gacc1);
  post(act2, n2, dg2, sacc2, gacc2);
}

// ---------------- K6: TWO nodes per wave, interleaved gathers, barrier-free
__global__ __launch_bounds__(256) void k_out(
    const unsigned short* __restrict__ Vfi16,
    const float* __restrict__ es, const float* __restrict__ esum,
    const float* __restrict__ m_in, const float* __restrict__ x_dst,
    const int* __restrict__ rowptr, const int2* __restrict__ sedge,
    float* __restrict__ out, int N)
{
  __shared__ float tr[4][64][9];
  int tid = threadIdx.x;
  int w = tid>>6, l = tid&63;
  int h = l>>4, e = l&15;
  int n1 = blockIdx.x*8 + w*2;
  int n2 = n1 + 1;
  if (n1 >= N) return;                   // legal: no barriers
  bool act2 = (n2 < N);

  int row1 = rowptr[n1], dg1 = rowptr[n1+1]-row1;
  int row2 = 0, dg2 = 0;
  float fm1[8], fm2[8];
  #pragma unroll
  for (int j=0;j<8;j++){ fm1[j]=0.f; fm2[j]=0.f; }
  {
    const float4* m4 = (const float4*)(m_in + (size_t)n1*8);
    float4 a=m4[0], b=m4[1];
    fm1[0]=a.x; fm1[1]=a.y; fm1[2]=a.z; fm1[3]=a.w;
    fm1[4]=b.x; fm1[5]=b.y; fm1[6]=b.z; fm1[7]=b.w;
  }
  if (act2){
    row2 = rowptr[n2]; dg2 = rowptr[n2+1]-row2;
    const float4* m4 = (const float4*)(m_in + (size_t)n2*8);
    float4 a=m4[0], b=m4[1];
    fm2[0]=a.x; fm2[1]=a.y; fm2[2]=a.z; fm2[3]=a.w;
    fm2[4]=b.x; fm2[5]=b.y; fm2[6]=b.z; fm2[7]=b.w;
  }
  float sh1 = esum[n1*4 + h];
  float invs1 = (dg1 > 0 && sh1 > 0.f) ? 1.f/sh1 : 0.f;
  float sh2 = act2 ? esum[n2*4 + h] : 0.f;
  float invs2 = (dg2 > 0 && sh2 > 0.f) ? 1.f/sh2 : 0.f;

  float vacc1[16], vacc2[16];
  #pragma unroll
  for (int j=0;j<16;j++){ vacc1[j]=0.f; vacc2[j]=0.f; }

  int mdg = max(dg1, dg2);
  for (int c0=0; c0<mdg; c0+=16){
    int cnt1 = dg1-c0, cnt2 = dg2-c0;
    int sna = (e < cnt1) ? sedge[row1+c0+e].x : 0;
    int snb = (e < cnt2) ? sedge[row2+c0+e].x : 0;
    float pe1 = (e < cnt1) ? es[(size_t)(row1+c0+e)*4 + h] : 0.f;
    float pe2 = (e < cnt2) ? es[(size_t)(row2+c0+e)*4 + h] : 0.f;
    const uint4* Ba = (const uint4*)(Vfi16 + (size_t)sna*96 + h*24);
    const uint4* Bb = (const uint4*)(Vfi16 + (size_t)snb*96 + h*24);
    uint4 a0=Ba[0], a1=Ba[1], a2=Ba[2];
    uint4 b0=Bb[0], b1=Bb[1], b2=Bb[2];

    {
      float dt = fmaf(bflo(a2.x),fm1[0], fmaf(bfhi(a2.x),fm1[1], fmaf(bflo(a2.y),fm1[2], fmaf(bfhi(a2.y),fm1[3],
                 fmaf(bflo(a2.z),fm1[4], fmaf(bfhi(a2.z),fm1[5], fmaf(bflo(a2.w),fm1[6], bfhi(a2.w)*fm1[7])))))));
      float wgt = dt * pe1;
      vacc1[0] =fmaf(bflo(a0.x),wgt,vacc1[0]);  vacc1[1] =fmaf(bfhi(a0.x),wgt,vacc1[1]);
      vacc1[2] =fmaf(bflo(a0.y),wgt,vacc1[2]);  vacc1[3] =fmaf(bfhi(a0.y),wgt,vacc1[3]);
      vacc1[4] =fmaf(bflo(a0.z),wgt,vacc1[4]);  vacc1[5] =fmaf(bfhi(a0.z),wgt,vacc1[5]);
      vacc1[6] =fmaf(bflo(a0.w),wgt,vacc1[6]);  vacc1[7] =fmaf(bfhi(a0.w),wgt,vacc1[7]);
      vacc1[8] =fmaf(bflo(a1.x),wgt,vacc1[8]);  vacc1[9] =fmaf(bfhi(a1.x),wgt,vacc1[9]);
      vacc1[10]=fmaf(bflo(a1.y),wgt,vacc1[10]); vacc1[11]=fmaf(bfhi(a1.y),wgt,vacc1[11]);
      vacc1[12]=fmaf(bflo(a1.z),wgt,vacc1[12]); vacc1[13]=fmaf(bfhi(a1.z),wgt,vacc1[13]);
      vacc1[14]=fmaf(bflo(a1.w),wgt,vacc1[14]); vacc1[15]=fmaf(bfhi(a1.w),wgt,vacc1[15]);
    }
    {
      float dt = fmaf(bflo(b2.x),fm2[0], fmaf(bfhi(b2.x),fm2[1], fmaf(bflo(b2.y),fm2[2], fmaf(bfhi(b2.y),fm2[3],
                 fmaf(bflo(b2.z),fm2[4], fmaf(bfhi(b2.z),fm2[5], fmaf(bflo(b2.w),fm2[6], bfhi(b2.w)*fm2[7])))))));
      float wgt = dt * pe2;
      vacc2[0] =fmaf(bflo(b0.x),wgt,vacc2[0]);  vacc2[1] =fmaf(bfhi(b0.x),wgt,vacc2[1]);
      vacc2[2] =fmaf(bflo(b0.y),wgt,vacc2[2]);  vacc2[3] =fmaf(bfhi(b0.y),wgt,vacc2[3]);
      vacc2[4] =fmaf(bflo(b0.z),wgt,vacc2[4]);  vacc2[5] =fmaf(bfhi(b0.z),wgt,vacc2[5]);
      vacc2[6] =fmaf(bflo(b0.w),wgt,vacc2[6]);  vacc2[7] =fmaf(bfhi(b0.w),wgt,vacc2[7]);
      vacc2[8] =fmaf(bflo(b1.x),wgt,vacc2[8]);  vacc2[9] =fmaf(bfhi(b1.x),wgt,vacc2[9]);
      vacc2[10]=fmaf(bflo(b1.y),wgt,vacc2[10]); vacc2[11]=fmaf(bfhi(b1.y),wgt,vacc2[11]);
      vacc2[12]=fmaf(bflo(b1.z),wgt,vacc2[12]); vacc2[13]=fmaf(bfhi(b1.z),wgt,vacc2[13]);
      vacc2[14]=fmaf(bflo(b1.w),wgt,vacc2[14]); vacc2[15]=fmaf(bfhi(b1.w),wgt,vacc2[15]);
    }
  }

  auto fin = [&](bool act, int n, float invs, float (&vacc)[16]){
    if (!act) return;
    float oval = 0.f;
    *(float4*)&tr[w][l][0] = make_float4(vacc[0],vacc[1],vacc[2],vacc[3]);
    *(float4*)&tr[w][l][4] = make_float4(vacc[4],vacc[5],vacc[6],vacc[7]);
    if (e < 8){
      float s = 0.f;
      #pragma unroll
      for (int ee=0; ee<16; ee++) s += tr[w][(h<<4)+ee][e];
      oval = s;
    }
    *(float4*)&tr[w][l][0] = make_float4(vacc[8],vacc[9],vacc[10],vacc[11]);
    *(float4*)&tr[w][l][4] = make_float4(vacc[12],vacc[13],vacc[14],vacc[15]);
    if (e >= 8){
      float s = 0.f;
      #pragma unroll
      for (int ee=0; ee<16; ee++) s += tr[w][(h<<4)+ee][e-8];
      oval = s;
    }
    out[(size_t)n*64 + l] = fmaf(oval, invs, x_dst[(size_t)n*64 + l]);
  };
  fin(true, n1, invs1, vacc1);
  fin(act2, n2, invs2, vacc2);
}

extern "C" void kernel_launch(void* const* d_in, const int* in_sizes, int n_in,
                              void* d_out, int out_size, void* d_ws, size_t ws_size,
                              hipStream_t stream)
{
  const float* x_src = (const float*)d_in[0];
  const float* x_dst = (const float*)d_in[1];
  const float* t_in  = (const float*)d_in[2];
  const float* m_in  = (const float*)d_in[3];
  const float* ef    = (const float*)d_in[4];
  const float* Wq    = (const float*)d_in[5];
  const float* Wk    = (const float*)d_in[6];
  const float* Wv    = (const float*)d_in[7];
  const float* Wt    = (const float*)d_in[8];
  const float* We    = (const float*)d_in[9];
  const float* Wi    = (const float*)d_in[10];
  const float* bi    = (const float*)d_in[11];
  const float* wiw   = (const float*)d_in[12];
  const float* sci   = (const float*)d_in[13];
  const int*   src   = (const int*)d_in[14];
  const int*   dst   = (const int*)d_in[15];
  int N = in_sizes[0] / 64;
  int E = in_sizes[14];
  float* out = (float*)d_out;

  char* p = (char*)d_ws;
  auto alloc = [&](size_t bytes)->char*{ char* r = p; p += (bytes + 255) & ~(size_t)255; return r; };
  float*          Qb    = (float*)alloc((size_t)N*64*4);
  unsigned short* KT16  = (unsigned short*)alloc((size_t)N*128*2);
  unsigned short* Vfi16 = (unsigned short*)alloc((size_t)N*96*2);
  float*          WeQ   = (float*)alloc((size_t)N*4*4);
  float*          esum  = (float*)alloc((size_t)N*4*4);
  float*          es    = (float*)alloc((size_t)E*4*4);
  int*            deg   = (int*)alloc((size_t)N*4);
  int*            fill  = (int*)alloc((size_t)N*4);
  int*            rowp  = (int*)alloc((size_t)(N+1)*4);
  int2*           sedge = (int2*)alloc((size_t)E*8);
  int             NB    = (N + 1023) / 1024;
  int*            bsum  = (int*)alloc((size_t)NB*4);

  hipMemsetAsync(deg,  0, (size_t)N*4, stream);
  hipMemsetAsync(fill, 0, (size_t)N*4, stream);

  k_proj<<<(N+63)/64, 256, 0, stream>>>(x_src, x_dst, Wq, Wk, Wt, Wv, We, Qb, KT16, Vfi16, WeQ, N);
  k_hist<<<(E+255)/256, 256, 0, stream>>>(dst, deg, E);
  k_scan1<<<NB, 1024, 0, stream>>>(deg, rowp, bsum, N);
  k_scan2<<<1, 64, 0, stream>>>(bsum, NB);
  k_scan3<<<NB, 1024, 0, stream>>>(rowp, bsum, N, E);
  k_scatter<<<(E+255)/256, 256, 0, stream>>>(dst, src, ef, rowp, fill, sedge, E);
  k_node<<<(N+7)/8, 256, 0, stream>>>(Qb, KT16, WeQ, t_in, rowp, sedge,
                                      Wi, bi, wiw, sci, es, esum, Vfi16, N);
  k_out<<<(N+7)/8, 256, 0, stream>>>(Vfi16, es, esum, m_in, x_dst, rowp, sedge, out, N);
}

// Round 20
// 339.985 us; speedup vs baseline: 1.0708x; 1.0708x over previous
//
#include <hip/hip_runtime.h>
#include <cmath>

// N=50000, E=800000, B=1, F=D=64, H=4, d=16, M=8.
// Edge kernels: lane = (head h=l>>4, edge-slot e=l&15). 16 edges/step/wave.
// Best measured config (r17): k_proj LDS-staged W; k_node single-node with
// fused bf16 KT rows (4 scattered 16B loads/chunk); k_out fused bf16 Vfi rows
// (3 scattered loads); two-pass wave-private LDS transpose; minimal barriers.

__device__ __forceinline__ float softplus_f(float z){
  return fmaxf(z, 0.f) + log1pf(__expf(-fabsf(z)));
}
__device__ __forceinline__ unsigned short f2bf(float x){   // RNE bf16
  unsigned int u = __float_as_uint(x);
  unsigned int r = (u + 0x7fffu + ((u>>16)&1u)) >> 16;
  return (unsigned short)r;
}
__device__ __forceinline__ unsigned int pack2bf(float a, float b){
  return (unsigned int)f2bf(a) | ((unsigned int)f2bf(b) << 16);
}
__device__ __forceinline__ float bflo(unsigned int u){ return __uint_as_float(u << 16); }
__device__ __forceinline__ float bfhi(unsigned int u){ return __uint_as_float(u & 0xffff0000u); }

// ---------------- K1: projections, W staged in LDS. Q f32; K,T -> KT16; V -> Vfi16
__global__ __launch_bounds__(256) void k_proj(
    const float* __restrict__ x_src, const float* __restrict__ x_dst,
    const float* __restrict__ Wq, const float* __restrict__ Wk,
    const float* __restrict__ Wt, const float* __restrict__ Wv,
    const float* __restrict__ We,
    float* __restrict__ Qo, unsigned short* __restrict__ KT16,
    unsigned short* __restrict__ Vfi16, float* __restrict__ WeQ, int N)
{
  __shared__ float sW[4*4096];
  int tid = threadIdx.x;
  {
    float4* dW = (float4*)sW;
    const float4* s0 = (const float4*)Wq;
    const float4* s1 = (const float4*)Wk;
    const float4* s2 = (const float4*)Wt;
    const float4* s3 = (const float4*)Wv;
    #pragma unroll
    for (int i=tid; i<1024; i+=256) dW[i]      = s0[i];
    #pragma unroll
    for (int i=tid; i<1024; i+=256) dW[1024+i] = s1[i];
    #pragma unroll
    for (int i=tid; i<1024; i+=256) dW[2048+i] = s2[i];
    #pragma unroll
    for (int i=tid; i<1024; i+=256) dW[3072+i] = s3[i];
  }
  __syncthreads();

  int l   = tid & 63;
  int mat = __builtin_amdgcn_readfirstlane(tid >> 6);
  int n   = blockIdx.x * 64 + l;
  if (n < N){
    const float* x = ((mat==0) ? x_dst : x_src) + (size_t)n*64;
    const float4* Wm4 = (const float4*)(sW + (mat<<12));
    const float4* We4 = (const float4*)We;

    float xr[64];
    const float4* x4 = (const float4*)x;
    #pragma unroll
    for (int i=0;i<16;i++){ float4 v=x4[i]; xr[4*i]=v.x; xr[4*i+1]=v.y; xr[4*i+2]=v.z; xr[4*i+3]=v.w; }

    float4* Q4 = (float4*)(Qo + (size_t)n*64);
    float weq0=0.f, weq1=0.f, weq2=0.f, weq3=0.f;
    #pragma unroll
    for (int jq=0;jq<16;jq++){
      float a0=0.f,a1=0.f,a2=0.f,a3=0.f;
      const float4* Wr4 = Wm4 + jq*64;
      #pragma unroll
      for (int f4=0;f4<16;f4++){
        float4 w0 = Wr4[f4], w1 = Wr4[16+f4], w2 = Wr4[32+f4], w3 = Wr4[48+f4];
        float x0=xr[4*f4], x1=xr[4*f4+1], x2=xr[4*f4+2], x3=xr[4*f4+3];
        a0=fmaf(w0.x,x0,a0); a0=fmaf(w0.y,x1,a0); a0=fmaf(w0.z,x2,a0); a0=fmaf(w0.w,x3,a0);
        a1=fmaf(w1.x,x0,a1); a1=fmaf(w1.y,x1,a1); a1=fmaf(w1.z,x2,a1); a1=fmaf(w1.w,x3,a1);
        a2=fmaf(w2.x,x0,a2); a2=fmaf(w2.y,x1,a2); a2=fmaf(w2.z,x2,a2); a2=fmaf(w2.w,x3,a2);
        a3=fmaf(w3.x,x0,a3); a3=fmaf(w3.y,x1,a3); a3=fmaf(w3.z,x2,a3); a3=fmaf(w3.w,x3,a3);
      }
      int hq = jq>>2, sq = jq&3;
      if (mat==0){
        Q4[jq] = make_float4(a0,a1,a2,a3);
        float4 we = We4[jq];
        float ws = we.x*a0 + we.y*a1 + we.z*a2 + we.w*a3;
        if      (jq <  4) weq0 += ws;
        else if (jq <  8) weq1 += ws;
        else if (jq < 12) weq2 += ws;
        else              weq3 += ws;
      } else if (mat==1){      // K slot: row 128 bf16, head base h*32, K at +0
        *(uint2*)(KT16 + (size_t)n*128 + hq*32 + sq*4) = make_uint2(pack2bf(a0,a1), pack2bf(a2,a3));
      } else if (mat==2){      // T slot: head base h*32, T at +16
        *(uint2*)(KT16 + (size_t)n*128 + hq*32 + 16 + sq*4) = make_uint2(pack2bf(a0,a1), pack2bf(a2,a3));
      } else {                 // V slot: row 96 bf16, head base h*24, V at +0
        *(uint2*)(Vfi16 + (size_t)n*96 + hq*24 + sq*4) = make_uint2(pack2bf(a0,a1), pack2bf(a2,a3));
      }
    }
    if (mat==0) *(float4*)(WeQ + (size_t)n*4) = make_float4(weq0,weq1,weq2,weq3);
  }
}

// ---------------- CSR build
__global__ __launch_bounds__(256) void k_hist(const int* __restrict__ dst, int* __restrict__ deg, int E){
  int i = blockIdx.x*256 + threadIdx.x;
  if (i < E) atomicAdd(&deg[dst[i]], 1);
}

__global__ __launch_bounds__(1024) void k_scan1(const int* __restrict__ deg, int* __restrict__ rowptr,
                                                int* __restrict__ bsum, int N){
  __shared__ int sh[1024];
  int t = threadIdx.x;
  int i = blockIdx.x*1024 + t;
  int v = (i < N) ? deg[i] : 0;
  sh[t] = v; __syncthreads();
  int x = v;
  for (int off=1; off<1024; off<<=1){
    int y = (t >= off) ? sh[t-off] : 0;
    __syncthreads();
    x += y; sh[t] = x;
    __syncthreads();
  }
  if (i < N) rowptr[i] = x - v;
  if (t == 1023) bsum[blockIdx.x] = x;
}

__global__ __launch_bounds__(64) void k_scan2(int* __restrict__ bsum, int nb){
  int l = threadIdx.x;
  int v0 = (l < nb) ? bsum[l] : 0;
  int v = v0;
  for (int off=1; off<64; off<<=1){
    int y = __shfl_up(v, off);
    if (l >= off) v += y;
  }
  if (l < nb) bsum[l] = v - v0;
}

__global__ __launch_bounds__(1024) void k_scan3(int* __restrict__ rowptr, const int* __restrict__ bsum,
                                                int N, int E){
  int i = blockIdx.x*1024 + threadIdx.x;
  if (i < N) rowptr[i] += bsum[blockIdx.x];
  if (i == 0) rowptr[N] = E;
}

__global__ __launch_bounds__(256) void k_scatter(const int* __restrict__ dst, const int* __restrict__ src,
                                                 const float* __restrict__ ef,
                                                 const int* __restrict__ rowptr,
                                                 int* __restrict__ fill,
                                                 int2* __restrict__ sedge, int E){
  int i = blockIdx.x*256 + threadIdx.x;
  if (i < E){
    int d_ = dst[i];
    int pos = rowptr[d_] + atomicAdd(&fill[d_], 1);
    sedge[pos] = make_int2(src[i], __float_as_int(ef[i]));
  }
}

// ---------------- K5: per-dst-node; 4 scattered loads/chunk (KT bf16 fused)
__global__ __launch_bounds__(256) void k_node(
    const float* __restrict__ Qb, const unsigned short* __restrict__ KT16,
    const float* __restrict__ WeQ, const float* __restrict__ t_in,
    const int* __restrict__ rowptr, const int2* __restrict__ sedge,
    const float* __restrict__ Wi, const float* __restrict__ bi,
    const float* __restrict__ wiw, const float* __restrict__ scale_i,
    float* __restrict__ es, float* __restrict__ esum,
    unsigned short* __restrict__ Vfi16, int N)
{
  __shared__ float sWi[128*17];
  __shared__ float sbi[128];
  __shared__ float swiw[128];
  __shared__ float sscale[8];
  __shared__ float g_sh[4][4][17];
  __shared__ float tr[4][64][9];
  int tid = threadIdx.x;
  for (int i=tid; i<128*17; i+=256) sWi[i] = Wi[i];
  if (tid < 128){ sbi[tid] = bi[tid]; swiw[tid] = wiw[tid]; }
  if (tid < 8)  sscale[tid] = __expf(scale_i[tid]);
  __syncthreads();                       // the ONLY block barrier (staging)

  int w = tid>>6, l = tid&63;
  int h = l>>4, e = l&15;
  int n = blockIdx.x*4 + w;
  bool act = (n < N);

  float sacc = 0.f;
  float gacc[16];
  #pragma unroll
  for (int j=0;j<16;j++) gacc[j] = 0.f;
  int dg = 0;

  if (act){
    int row0 = rowptr[n];
    dg = rowptr[n+1] - row0;
    const float4* q4 = (const float4*)(Qb + (size_t)n*64 + (h<<4));
    float q[16];
    #pragma unroll
    for (int j=0;j<4;j++){
      float4 v = q4[j];
      q[4*j]=v.x*0.25f; q[4*j+1]=v.y*0.25f; q[4*j+2]=v.z*0.25f; q[4*j+3]=v.w*0.25f;
    }
    float weq = WeQ[n*4 + h] * 0.25f;

    int2 pv = (dg > 0 && e < dg) ? sedge[row0+e] : make_int2(0,0);
    for (int c0=0; c0<dg; c0+=16){
      int cnt = dg - c0;
      int2 cur = pv;
      if (c0+16 < dg && e < cnt-16) pv = sedge[row0+c0+16+e];
      int sn = cur.x;
      float efv = __int_as_float(cur.y);
      // one contiguous 64B per lane: [K_h 32B | T_h 32B]
      const uint4* G4 = (const uint4*)(KT16 + ((size_t)sn<<7) + (h<<5));
      uint4 g0=G4[0], g1=G4[1];          // K_h (16 bf16)
      uint4 g2=G4[2], g3=G4[3];          // T_h (16 bf16)
      float d = 0.f;
      d=fmaf(bflo(g0.x),q[0],d);  d=fmaf(bfhi(g0.x),q[1],d);
      d=fmaf(bflo(g0.y),q[2],d);  d=fmaf(bfhi(g0.y),q[3],d);
      d=fmaf(bflo(g0.z),q[4],d);  d=fmaf(bfhi(g0.z),q[5],d);
      d=fmaf(bflo(g0.w),q[6],d);  d=fmaf(bfhi(g0.w),q[7],d);
      d=fmaf(bflo(g1.x),q[8],d);  d=fmaf(bfhi(g1.x),q[9],d);
      d=fmaf(bflo(g1.y),q[10],d); d=fmaf(bfhi(g1.y),q[11],d);
      d=fmaf(bflo(g1.z),q[12],d); d=fmaf(bfhi(g1.z),q[13],d);
      d=fmaf(bflo(g1.w),q[14],d); d=fmaf(bfhi(g1.w),q[15],d);
      float p = __expf(fmaf(efv, weq, d));
      if (e >= cnt) p = 0.f;
      if (e < cnt)  es[(size_t)(row0+c0+e)*4 + h] = p;
      sacc += p;
      gacc[0] =fmaf(bflo(g2.x),p,gacc[0]);  gacc[1] =fmaf(bfhi(g2.x),p,gacc[1]);
      gacc[2] =fmaf(bflo(g2.y),p,gacc[2]);  gacc[3] =fmaf(bfhi(g2.y),p,gacc[3]);
      gacc[4] =fmaf(bflo(g2.z),p,gacc[4]);  gacc[5] =fmaf(bfhi(g2.z),p,gacc[5]);
      gacc[6] =fmaf(bflo(g2.w),p,gacc[6]);  gacc[7] =fmaf(bfhi(g2.w),p,gacc[7]);
      gacc[8] =fmaf(bflo(g3.x),p,gacc[8]);  gacc[9] =fmaf(bfhi(g3.x),p,gacc[9]);
      gacc[10]=fmaf(bflo(g3.y),p,gacc[10]); gacc[11]=fmaf(bfhi(g3.y),p,gacc[11]);
      gacc[12]=fmaf(bflo(g3.z),p,gacc[12]); gacc[13]=fmaf(bfhi(g3.z),p,gacc[13]);
      gacc[14]=fmaf(bflo(g3.w),p,gacc[14]); gacc[15]=fmaf(bfhi(g3.w),p,gacc[15]);
    }
  }

  // softmax denominator: reduce over the 16 edge-slot lanes
  sacc += __shfl_xor(sacc,1); sacc += __shfl_xor(sacc,2);
  sacc += __shfl_xor(sacc,4); sacc += __shfl_xor(sacc,8);
  if (act && e == 0) esum[n*4 + h] = sacc;
  float invs = (dg > 0) ? 1.f/sacc : 0.f;

  // two-pass transpose-reduce, wave-private tile, barrier-free
  float gval = 0.f;
  *(float4*)&tr[w][l][0] = make_float4(gacc[0],gacc[1],gacc[2],gacc[3]);
  *(float4*)&tr[w][l][4] = make_float4(gacc[4],gacc[5],gacc[6],gacc[7]);
  if (e < 8){
    float s = 0.f;
    #pragma unroll
    for (int ee=0; ee<16; ee++) s += tr[w][(h<<4)+ee][e];
    gval = s;
  }
  *(float4*)&tr[w][l][0] = make_float4(gacc[8],gacc[9],gacc[10],gacc[11]);
  *(float4*)&tr[w][l][4] = make_float4(gacc[12],gacc[13],gacc[14],gacc[15]);
  if (e >= 8){
    float s = 0.f;
    #pragma unroll
    for (int ee=0; ee<16; ee++) s += tr[w][(h<<4)+ee][e-8];
    gval = s;
  }
  if (act){
    g_sh[w][h][e] = gval * invs;
    if (l < 4) g_sh[w][l][16] = t_in[n];
  }

  if (act){
    float wi1[17], wi2[17];
    #pragma unroll
    for (int j=0;j<17;j++){ wi1[j] = sWi[l*17 + j]; wi2[j] = sWi[(l+64)*17 + j]; }
    float b1 = sbi[l],  b2 = sbi[l+64];
    float wv1 = swiw[l], wv2 = swiw[l+64];
    float z1[4], z2[4];
    #pragma unroll
    for (int h2=0; h2<4; h2++){
      float a1=b1, a2=b2;
      #pragma unroll
      for (int j=0;j<17;j++){
        float inj = g_sh[w][h2][j];
        a1 = fmaf(wi1[j], inj, a1);
        a2 = fmaf(wi2[j], inj, a2);
      }
      float u1 = __fdividef(1.f, 1.f + __expf(-a1));
      float u2 = __fdividef(1.f, 1.f + __expf(-a2));
      float p1 = u1*wv1, p2 = u2*wv2;
      p1 += __shfl_xor(p1,1); p1 += __shfl_xor(p1,2); p1 += __shfl_xor(p1,4); p1 += __shfl_xor(p1,8);
      p2 += __shfl_xor(p2,1); p2 += __shfl_xor(p2,2); p2 += __shfl_xor(p2,4); p2 += __shfl_xor(p2,8);
      z1[h2] = p1; z2[h2] = p2;
    }
    if (e == 0){
      int m1 = h;
      float sc1 = sscale[m1], sc2 = sscale[m1+4];
      #pragma unroll
      for (int h2=0; h2<4; h2++){
        // fi slot: row 96 bf16, head h2 base h2*24, fi at +16
        Vfi16[(size_t)n*96 + h2*24 + 16 + m1    ] = f2bf(sc1*softplus_f(z1[h2]/sc1));
        Vfi16[(size_t)n*96 + h2*24 + 16 + m1 + 4] = f2bf(sc2*softplus_f(z2[h2]/sc2));
      }
    }
  }
}

// ---------------- K6: 3 scattered loads/chunk (Vfi bf16 fused), barrier-free
__global__ __launch_bounds__(256) void k_out(
    const unsigned short* __restrict__ Vfi16,
    const float* __restrict__ es, const float* __restrict__ esum,
    const float* __restrict__ m_in, const float* __restrict__ x_dst,
    const int* __restrict__ rowptr, const int2* __restrict__ sedge,
    float* __restrict__ out, int N)
{
  __shared__ float tr[4][64][9];
  int tid = threadIdx.x;
  int w = tid>>6, l = tid&63;
  int h = l>>4, e = l&15;
  int n = blockIdx.x*4 + w;
  if (n >= N) return;                    // legal: no barriers

  float vacc[16];
  #pragma unroll
  for (int j=0;j<16;j++) vacc[j] = 0.f;

  int row0 = rowptr[n];
  int dg = rowptr[n+1] - row0;
  float fm[8];
  const float4* m4 = (const float4*)(m_in + (size_t)n*8);
  float4 fma_=m4[0], fmb_=m4[1];
  fm[0]=fma_.x; fm[1]=fma_.y; fm[2]=fma_.z; fm[3]=fma_.w;
  fm[4]=fmb_.x; fm[5]=fmb_.y; fm[6]=fmb_.z; fm[7]=fmb_.w;
  float sh = esum[n*4 + h];
  float invs = (dg > 0 && sh > 0.f) ? 1.f/sh : 0.f;

  int2 pv = (dg > 0 && e < dg) ? sedge[row0+e] : make_int2(0,0);
  for (int c0=0; c0<dg; c0+=16){
    int cnt = dg - c0;
    int sn = pv.x;
    if (c0+16 < dg && e < cnt-16) pv = sedge[row0+c0+16+e];
    float pe = (e < cnt) ? es[(size_t)(row0+c0+e)*4 + h] : 0.f;
    // one contiguous 48B per lane: [V_h 32B | fi_h 16B]
    const uint4* B4 = (const uint4*)(Vfi16 + (size_t)sn*96 + h*24);
    uint4 b0=B4[0], b1=B4[1];            // V_h (16 bf16)
    uint4 b2=B4[2];                      // fi_h (8 bf16)
    float dt = fmaf(bflo(b2.x),fm[0], fmaf(bfhi(b2.x),fm[1], fmaf(bflo(b2.y),fm[2], fmaf(bfhi(b2.y),fm[3],
               fmaf(bflo(b2.z),fm[4], fmaf(bfhi(b2.z),fm[5], fmaf(bflo(b2.w),fm[6], bfhi(b2.w)*fm[7])))))));
    float wgt = dt * pe;
    vacc[0] =fmaf(bflo(b0.x),wgt,vacc[0]);  vacc[1] =fmaf(bfhi(b0.x),wgt,vacc[1]);
    vacc[2] =fmaf(bflo(b0.y),wgt,vacc[2]);  vacc[3] =fmaf(bfhi(b0.y),wgt,vacc[3]);
    vacc[4] =fmaf(bflo(b0.z),wgt,vacc[4]);  vacc[5] =fmaf(bfhi(b0.z),wgt,vacc[5]);
    vacc[6] =fmaf(bflo(b0.w),wgt,vacc[6]);  vacc[7] =fmaf(bfhi(b0.w),wgt,vacc[7]);
    vacc[8] =fmaf(bflo(b1.x),wgt,vacc[8]);  vacc[9] =fmaf(bfhi(b1.x),wgt,vacc[9]);
    vacc[10]=fmaf(bflo(b1.y),wgt,vacc[10]); vacc[11]=fmaf(bfhi(b1.y),wgt,vacc[11]);
    vacc[12]=fmaf(bflo(b1.z),wgt,vacc[12]); vacc[13]=fmaf(bfhi(b1.z),wgt,vacc[13]);
    vacc[14]=fmaf(bflo(b1.w),wgt,vacc[14]); vacc[15]=fmaf(bfhi(b1.w),wgt,vacc[15]);
  }

  float oval = 0.f;
  *(float4*)&tr[w][l][0] = make_float4(vacc[0],vacc[1],vacc[2],vacc[3]);
  *(float4*)&tr[w][l][4] = make_float4(vacc[4],vacc[5],vacc[6],vacc[7]);
  if (e < 8){
    float s = 0.f;
    #pragma unroll
    for (int ee=0; ee<16; ee++) s += tr[w][(h<<4)+ee][e];
    oval = s;
  }
  *(float4*)&tr[w][l][0] = make_float4(vacc[8],vacc[9],vacc[10],vacc[11]);
  *(float4*)&tr[w][l][4] = make_float4(vacc[12],vacc[13],vacc[14],vacc[15]);
  if (e >= 8){
    float s = 0.f;
    #pragma unroll
    for (int ee=0; ee<16; ee++) s += tr[w][(h<<4)+ee][e-8];
    oval = s;
  }
  out[(size_t)n*64 + l] = fmaf(oval, invs, x_dst[(size_t)n*64 + l]);
}

extern "C" void kernel_launch(void* const* d_in, const int* in_sizes, int n_in,
                              void* d_out, int out_size, void* d_ws, size_t ws_size,
                              hipStream_t stream)
{
  const float* x_src = (const float*)d_in[0];
  const float* x_dst = (const float*)d_in[1];
  const float* t_in  = (const float*)d_in[2];
  const float* m_in  = (const float*)d_in[3];
  const float* ef    = (const float*)d_in[4];
  const float* Wq    = (const float*)d_in[5];
  const float* Wk    = (const float*)d_in[6];
  const float* Wv    = (const float*)d_in[7];
  const float* Wt    = (const float*)d_in[8];
  const float* We    = (const float*)d_in[9];
  const float* Wi    = (const float*)d_in[10];
  const float* bi    = (const float*)d_in[11];
  const float* wiw   = (const float*)d_in[12];
  const float* sci   = (const float*)d_in[13];
  const int*   src   = (const int*)d_in[14];
  const int*   dst   = (const int*)d_in[15];
  int N = in_sizes[0] / 64;
  int E = in_sizes[14];
  float* out = (float*)d_out;

  char* p = (char*)d_ws;
  auto alloc = [&](size_t bytes)->char*{ char* r = p; p += (bytes + 255) & ~(size_t)255; return r; };
  float*          Qb    = (float*)alloc((size_t)N*64*4);
  unsigned short* KT16  = (unsigned short*)alloc((size_t)N*128*2);
  unsigned short* Vfi16 = (unsigned short*)alloc((size_t)N*96*2);
  float*          WeQ   = (float*)alloc((size_t)N*4*4);
  float*          esum  = (float*)alloc((size_t)N*4*4);
  float*          es    = (float*)alloc((size_t)E*4*4);
  int*            deg   = (int*)alloc((size_t)N*4);
  int*            fill  = (int*)alloc((size_t)N*4);
  int*            rowp  = (int*)alloc((size_t)(N+1)*4);
  int2*           sedge = (int2*)alloc((size_t)E*8);
  int             NB    = (N + 1023) / 1024;
  int*            bsum  = (int*)alloc((size_t)NB*4);

  hipMemsetAsync(deg,  0, (size_t)N*4, stream);
  hipMemsetAsync(fill, 0, (size_t)N*4, stream);

  k_proj<<<(N+63)/64, 256, 0, stream>>>(x_src, x_dst, Wq, Wk, Wt, Wv, We, Qb, KT16, Vfi16, WeQ, N);
  k_hist<<<(E+255)/256, 256, 0, stream>>>(dst, deg, E);
  k_scan1<<<NB, 1024, 0, stream>>>(deg, rowp, bsum, N);
  k_scan2<<<1, 64, 0, stream>>>(bsum, NB);
  k_scan3<<<NB, 1024, 0, stream>>>(rowp, bsum, N, E);
  k_scatter<<<(E+255)/256, 256, 0, stream>>>(dst, src, ef, rowp, fill, sedge, E);
  k_node<<<(N+3)/4, 256, 0, stream>>>(Qb, KT16, WeQ, t_in, rowp, sedge,
                                      Wi, bi, wiw, sci, es, esum, Vfi16, N);
  k_out<<<(N+3)/4, 256, 0, stream>>>(Vfi16, es, esum, m_in, x_dst, rowp, sedge, out, N);
}